// Round 8
// baseline (465.491 us; speedup 1.0000x reference)
//
#include <hip/hip_runtime.h>
#include <hip/hip_bf16.h>

#define HWDIM 1024             // 32*32
#define DDIM 256
#define KCODES 1024
#define NROWS 32768            // 32 * 1024
#define BSTRIDE (DDIM * HWDIM) // per-batch stride = 262144
#define GUARD 1.5e-4f          // certified gap (covers 2x dist roundings @256 + split err)

typedef __attribute__((ext_vector_type(8))) short short8;
typedef __attribute__((ext_vector_type(4))) float f32x4;
typedef unsigned long long ull;

// ---- ws byte layout ----
// wT     @0        (1048576)  fp32 codebook transposed [256][1024] (full fallback)
// ss     @1048576  (4096)     ||e_k||^2 numpy-pairwise
// kkarr  @1052672  (131072)   final code index per row (u32)
// wlist  @1183744  (131072)   worklist: rows needing FULL exact rescan
// hist   @1314816  (4096)
// plist  @1318912  (131072)   pairlist: rows needing exact {k1,k2} compare  (n | k2<<16)
// loss   @1449984  (8)        double
// wcount @1449992  (4)
// pcount @1449996  (4)
// ---- scratch in d_out encodings region (fully overwritten later by k_quantenc) ----
// ob = (char*)d_out + 33554448: wh8 @0 (524288), wl8 @524288 (524288)

__device__ __forceinline__ unsigned short f2bf(float v) {
  __hip_bfloat16 b = __float2bfloat16(v);
  return *reinterpret_cast<unsigned short*>(&b);
}
__device__ __forceinline__ float bf2f(unsigned short u) {
  __hip_bfloat16 b;
  *reinterpret_cast<unsigned short*>(&b) = u;
  return __bfloat162float(b);
}
__device__ __forceinline__ ull pk(float d, int k) {
  unsigned ub = __float_as_uint(d);
  ub = (ub & 0x80000000u) ? ~ub : (ub | 0x80000000u);  // monotone total order
  return ((ull)ub << 32) | (unsigned)k;
}
__device__ __forceinline__ float keyq(ull key) {
  unsigned ub = (unsigned)(key >> 32);
  unsigned orig = (ub & 0x80000000u) ? (ub & 0x7FFFFFFFu) : ~ub;
  return __uint_as_float(orig);
}
__device__ __forceinline__ float keyq32(unsigned ub) {
  unsigned orig = (ub & 0x80000000u) ? (ub & 0x7FFFFFFFu) : ~ub;
  return __uint_as_float(orig);
}

// numpy-exact pairwise sum of squares over 128 elements
__device__ __forceinline__ float pair128_sq(const float* p, int stride) {
  float a[8];
#pragma unroll
  for (int j = 0; j < 8; ++j) { float v = p[j * stride]; a[j] = __fmul_rn(v, v); }
  for (int i = 8; i < 128; i += 8) {
#pragma unroll
    for (int j = 0; j < 8; ++j) {
      float v = p[(i + j) * stride];
      a[j] = __fadd_rn(a[j], __fmul_rn(v, v));
    }
  }
  float s01 = __fadd_rn(a[0], a[1]), s23 = __fadd_rn(a[2], a[3]);
  float s45 = __fadd_rn(a[4], a[5]), s67 = __fadd_rn(a[6], a[7]);
  return __fadd_rn(__fadd_rn(s01, s23), __fadd_rn(s45, s67));
}

// prep: w bf16 hi/lo split [oct][k][8], wT transpose, ss, inits. grid 128.
__global__ __launch_bounds__(256) void k_prep(
    const float* __restrict__ w, float* __restrict__ wT, float* __restrict__ ss,
    int* __restrict__ hist, double* __restrict__ loss,
    int* __restrict__ wcount, int* __restrict__ pcount,
    unsigned short* __restrict__ wh8, unsigned short* __restrict__ wl8) {
  __shared__ float tile[64][65];
  const int t = threadIdx.x;
  int g = blockIdx.x * 256 + t;   // 32768 = 1024 k x 32 octets
  {
    int k = g >> 5, oct = g & 31;
    const float* p = w + k * DDIM + oct * 8;
    short8 hv, lv;
#pragma unroll
    for (int j = 0; j < 8; ++j) {
      float v = p[j];
      unsigned short h = f2bf(v);
      unsigned short l = f2bf(__fsub_rn(v, bf2f(h)));
      hv[j] = (short)h; lv[j] = (short)l;
    }
    *(short8*)&wh8[oct * 8192 + k * 8] = hv;
    *(short8*)&wl8[oct * 8192 + k * 8] = lv;
  }
  if (g < KCODES) {
    hist[g] = 0;
    const float* p = w + g * DDIM;
    ss[g] = __fadd_rn(pair128_sq(p, 1), pair128_sq(p + 128, 1));
  }
  if (g == 0) { *loss = 0.0; *wcount = 0; *pcount = 0; }
  // transpose (blocks 0..63): w[k][d] -> wT[d][k], 64x64 tiles
  if (blockIdx.x < 64) {
    const int k0 = (blockIdx.x & 15) * 64, d0 = (blockIdx.x >> 4) * 64;
    const int c = t & 63, r = t >> 6;
#pragma unroll
    for (int m = 0; m < 16; ++m)
      tile[r + m * 4][c] = w[(k0 + r + m * 4) * DDIM + d0 + c];
    __syncthreads();
#pragma unroll
    for (int m = 0; m < 16; ++m)
      wT[(size_t)(d0 + r + m * 4) * KCODES + k0 + c] = tile[c][r + m * 4];
  }
}

// single-pass MFMA argmin: block = 32 rows x ALL 1024 codes. grid 1024.
// TRUE 4 waves/SIMD: LDS 37 KB -> 4 blocks/CU AND __launch_bounds__(256,4)
// forces VGPR <= 128 (R5 never achieved this: 140 regs capped it at ~2).
// Per wave: rt=2 x ct=2 tile, 32-code column per 128-code kb, 8 kbs.
// rb3 index-free (32-bit dist key). Nontemporal x staging protects B's L2.
__global__ __launch_bounds__(256, 4) void k_argmfma(
    const float* __restrict__ in,
    const unsigned short* __restrict__ wh8, const unsigned short* __restrict__ wl8,
    const float* __restrict__ ss, unsigned* __restrict__ kkarr,
    int* __restrict__ wlist, int* __restrict__ wcount,
    int* __restrict__ plist, int* __restrict__ pcount) {
  __shared__ __align__(16) unsigned short Ah[32 * 32 * 8];  // 16 KB
  __shared__ __align__(16) unsigned short Al[32 * 32 * 8];  // 16 KB
  __shared__ __align__(16) float ss_l[1024];                // 4 KB
  __shared__ ull best1[32], best2[32];
  __shared__ unsigned best3[32];

  const int t = threadIdx.x;
  const int n0 = blockIdx.x * 32;       // 32 | 1024 -> single batch per block
  const int b = n0 >> 10, hw0 = n0 & 1023;

  const int wv = t >> 6, ln = t & 63;
  const int cw = wv * 32;                // wave's 32-code column within each kb
  const int l15 = ln & 15, quad = ln >> 4;

  // ---- in-kernel split of x rows into LDS (identical h/l formulas, R5 layout) ----
  {
    const int hw = t & 31, dg = t >> 5;  // 32 rows, 8 d-groups of 32
    const float* xp = in + b * BSTRIDE + hw0 + hw;
#pragma unroll
    for (int dd = 0; dd < 32; dd += 2) {
      int d = dg * 32 + dd;
      float f0 = __builtin_nontemporal_load(&xp[d * HWDIM]);
      float f1 = __builtin_nontemporal_load(&xp[(d + 1) * HWDIM]);
      unsigned short h0 = f2bf(f0);
      unsigned short l0 = f2bf(__fsub_rn(f0, bf2f(h0)));
      unsigned short h1 = f2bf(f1);
      unsigned short l1 = f2bf(__fsub_rn(f1, bf2f(h1)));
      int base = ((d >> 3) * 32 + hw) * 8 + (d & 7);   // d even -> u32 pack ok
      *(unsigned*)&Ah[base] = (unsigned)h0 | ((unsigned)h1 << 16);
      *(unsigned*)&Al[base] = (unsigned)l0 | ((unsigned)l1 << 16);
    }
  }
  *(float4*)&ss_l[t * 4] = *(const float4*)&ss[t * 4];
  if (t < 32) { best1[t] = ~0ull; best2[t] = ~0ull; best3[t] = 0xFFFFFFFFu; }
  __syncthreads();

  ull rb1[8], rb2[8];                    // running top-2 per (rt,reg) row slot
  unsigned rb3[8];                       // 3rd-best DIST KEY only (no index)
#pragma unroll
  for (int i = 0; i < 8; ++i) { rb1[i] = ~0ull; rb2[i] = ~0ull; rb3[i] = 0xFFFFFFFFu; }

  for (int kb = 0; kb < 8; ++kb) {       // 8 x 128-code blocks
    const int cb = kb * 128 + cw;
    f32x4 acc[2][2];
#pragma unroll
    for (int rt = 0; rt < 2; ++rt)
#pragma unroll
      for (int ct = 0; ct < 2; ++ct) acc[rt][ct] = (f32x4){0.f, 0.f, 0.f, 0.f};

#pragma unroll
    for (int ki = 0; ki < 8; ++ki) {
      const int obase = ki * 4 + quad;
      short8 ah[2], al[2], bh[2], bl[2];
#pragma unroll
      for (int rt = 0; rt < 2; ++rt) {
        int row = rt * 16 + l15;
        ah[rt] = *(const short8*)&Ah[(obase * 32 + row) * 8];
        al[rt] = *(const short8*)&Al[(obase * 32 + row) * 8];
      }
#pragma unroll
      for (int ct = 0; ct < 2; ++ct) {
        int off = obase * 8192 + (cb + ct * 16 + l15) * 8;
        bh[ct] = *(const short8*)&wh8[off];
        bl[ct] = *(const short8*)&wl8[off];
      }
      __builtin_amdgcn_s_setprio(1);
#pragma unroll
      for (int rt = 0; rt < 2; ++rt)
#pragma unroll
        for (int ct = 0; ct < 2; ++ct) {
          acc[rt][ct] = __builtin_amdgcn_mfma_f32_16x16x32_bf16(ah[rt], bh[ct], acc[rt][ct], 0, 0, 0);
          acc[rt][ct] = __builtin_amdgcn_mfma_f32_16x16x32_bf16(ah[rt], bl[ct], acc[rt][ct], 0, 0, 0);
          acc[rt][ct] = __builtin_amdgcn_mfma_f32_16x16x32_bf16(al[rt], bh[ct], acc[rt][ct], 0, 0, 0);
        }
      __builtin_amdgcn_s_setprio(0);
    }

    // fold this kb's 32 codes into running per-row top-3 (lane-local)
    float sv[2];
#pragma unroll
    for (int ct = 0; ct < 2; ++ct) sv[ct] = ss_l[cb + ct * 16 + l15];
#pragma unroll
    for (int rt = 0; rt < 2; ++rt)
#pragma unroll
      for (int reg = 0; reg < 4; ++reg) {
        int idx = rt * 4 + reg;
        ull b1 = rb1[idx], b2 = rb2[idx];
        unsigned b3 = rb3[idx];
#pragma unroll
        for (int ct = 0; ct < 2; ++ct) {
          float q = fmaf(-2.f, acc[rt][ct][reg], sv[ct]);
          ull key = pk(q, cb + ct * 16 + l15);
          unsigned k32 = (unsigned)(key >> 32);
          if (key < b1)      { b3 = (unsigned)(b2 >> 32); b2 = b1; b1 = key; }
          else if (key < b2) { b3 = (unsigned)(b2 >> 32); b2 = key; }
          else if (k32 < b3) { b3 = k32; }
        }
        rb1[idx] = b1; rb2[idx] = b2; rb3[idx] = b3;
      }
  }

  // three-pass block merge: global best, 2nd, 3rd(dist-key only)
#pragma unroll
  for (int rt = 0; rt < 2; ++rt)
#pragma unroll
    for (int reg = 0; reg < 4; ++reg)
      atomicMin(&best1[rt * 16 + quad * 4 + reg], rb1[rt * 4 + reg]);
  __syncthreads();
#pragma unroll
  for (int rt = 0; rt < 2; ++rt)
#pragma unroll
    for (int reg = 0; reg < 4; ++reg) {
      int row = rt * 16 + quad * 4 + reg;
      int idx = rt * 4 + reg;
      ull sub = (rb1[idx] == best1[row]) ? rb2[idx] : rb1[idx];
      atomicMin(&best2[row], sub);
    }
  __syncthreads();
#pragma unroll
  for (int rt = 0; rt < 2; ++rt)
#pragma unroll
    for (int reg = 0; reg < 4; ++reg) {
      int row = rt * 16 + quad * 4 + reg;
      int idx = rt * 4 + reg;
      ull b1 = best1[row], b2 = best2[row];
      unsigned c = (rb1[idx] != b1 && rb1[idx] != b2) ? (unsigned)(rb1[idx] >> 32)
                 : ((rb2[idx] != b1 && rb2[idx] != b2) ? (unsigned)(rb2[idx] >> 32)
                                                       : rb3[idx]);
      atomicMin(&best3[row], c);
    }
  __syncthreads();
  if (t < 32) {
    ull k1 = best1[t];
    kkarr[n0 + t] = (unsigned)(k1 & 0xFFFFFFFFull);
    float q1 = keyq(k1);
    if (!(keyq(best2[t]) - q1 > GUARD)) {
      if (keyq32(best3[t]) - q1 > GUARD) {
        // exact argmin is provably in {k1, k2}: cheap pair recheck
        int p = atomicAdd(pcount, 1);
        plist[p] = (n0 + t) | ((int)(best2[t] & 0xFFFFFFFFull) << 16);
      } else {
        int p = atomicAdd(wcount, 1);
        wlist[p] = n0 + t;
      }
    }
  }
}

// recheck kernel: cheap exact {k1,k2} compare for pair rows, full 1024-code
// exact rescan only for rows with gap3 <= GUARD. grid 1024.
// Both paths replicate the verified numpy-exact FP op order.
__global__ __launch_bounds__(256) void k_fallback(
    const float* __restrict__ in, const float* __restrict__ w,
    const float* __restrict__ wT, const float* __restrict__ ss,
    const int* __restrict__ wlist, const int* __restrict__ wcount,
    const int* __restrict__ plist, const int* __restrict__ pcount,
    unsigned* __restrict__ kkarr) {
  __shared__ float xrow[256];
  __shared__ float rsh;
  __shared__ ull bmin;
  __shared__ ull pkeys[2];
  const int t = threadIdx.x;

  // ---- pair rows: exact dist for k1,k2 only (identical op order to full path) ----
  const int pc = *pcount;
  for (int i = blockIdx.x; i < pc; i += gridDim.x) {
    const int pe = plist[i];
    const int n = pe & 0xFFFF;
    const unsigned k2 = ((unsigned)pe) >> 16;
    const unsigned k1 = kkarr[n];
    const int b = n >> 10, hw = n & 1023;
    xrow[t] = in[b * BSTRIDE + t * HWDIM + hw];
    __syncthreads();
    if (t == 0) rsh = __fadd_rn(pair128_sq(xrow, 1), pair128_sq(xrow + 128, 1));
    __syncthreads();
    if (t < 2) {
      unsigned k = t ? k2 : k1;
      const float* wr = w + (size_t)k * DDIM;   // same values as wT column k
      float m = 0.f;
      for (int d = 0; d < 256; ++d) m = fmaf(xrow[d], wr[d], m);
      float dist = fmaf(-2.f, m, __fadd_rn(rsh, ss[k]));
      pkeys[t] = pk(dist, (int)k);
    }
    __syncthreads();
    if (t == 0) {
      ull kmin = pkeys[0] < pkeys[1] ? pkeys[0] : pkeys[1];
      kkarr[n] = (unsigned)(kmin & 0xFFFFFFFFull);
    }
    __syncthreads();
  }

  // ---- full rows: exact rescan of all 1024 codes (unchanged verified path) ----
  const int cnt = *wcount;
  for (int i = blockIdx.x; i < cnt; i += gridDim.x) {
    const int n = wlist[i];
    const int b = n >> 10, hw = n & 1023;
    xrow[t] = in[b * BSTRIDE + t * HWDIM + hw];
    if (t == 0) bmin = ~0ull;
    __syncthreads();
    if (t == 0) rsh = __fadd_rn(pair128_sq(xrow, 1), pair128_sq(xrow + 128, 1));
    __syncthreads();
    float m[4] = {0.f, 0.f, 0.f, 0.f};
    for (int d = 0; d < 256; ++d) {
      float xv = xrow[d];
      const float* wd = wT + (size_t)d * KCODES + t;
      m[0] = fmaf(xv, wd[0], m[0]);
      m[1] = fmaf(xv, wd[256], m[1]);
      m[2] = fmaf(xv, wd[512], m[2]);
      m[3] = fmaf(xv, wd[768], m[3]);
    }
    ull lb = ~0ull;
#pragma unroll
    for (int j = 0; j < 4; ++j) {
      int k = t + j * 256;
      float dist = fmaf(-2.f, m[j], __fadd_rn(rsh, ss[k]));
      ull key = pk(dist, k);
      if (key < lb) lb = key;
    }
    atomicMin(&bmin, lb);
    __syncthreads();
    if (t == 0) kkarr[n] = (unsigned)(bmin & 0xFFFFFFFFull);
    __syncthreads();
  }
}

// fused streaming epilogue: one-hot enc rows written DIRECTLY (zeros + the one),
// quantized_st, loss, hist. block = 64 rows x (64-d chunk, 256-code chunk). grid 2048.
__global__ __launch_bounds__(256) void k_quantenc(
    const float* __restrict__ in, const float* __restrict__ w,
    const unsigned* __restrict__ kkarr, int* __restrict__ hist,
    float* __restrict__ enc, float* __restrict__ outq, double* __restrict__ loss) {
  __shared__ float wrow[64][65];
  __shared__ unsigned kk[64];
  __shared__ double red[256];

  const int t = threadIdx.x;
  const int q = blockIdx.x & 3;
  const int n0 = (blockIdx.x >> 2) * 64;
  const int dc = q * 64;          // d chunk for outq/loss
  const int c0 = q * 256;         // code chunk for enc rows
  const int b = n0 >> 10, hw0 = n0 & 1023;

  if (t < 64) kk[t] = kkarr[n0 + t];
  __syncthreads();

  if (q == 0 && t < 64) atomicAdd(&hist[kk[t]], 1);

  // enc: 64 rows x 256 codes = 8192 float2 (base is 8B-aligned only -> float2)
#pragma unroll 4
  for (int m = 0; m < 32; ++m) {
    int u = m * 256 + t;
    int r = u >> 7, c2 = u & 127;
    int cbase = c0 + c2 * 2;
    unsigned kr = kk[r];
    float2 v;
    v.x = (cbase == (int)kr) ? 1.0f : 0.0f;
    v.y = (cbase + 1 == (int)kr) ? 1.0f : 0.0f;
    *(float2*)&enc[(size_t)(n0 + r) * 1024 + cbase] = v;
  }

  // stage the 64 codebook rows' 64-d slice (gather; w is L2-resident)
#pragma unroll
  for (int m = 0; m < 16; ++m) {
    int u = t + m * 256;
    int r = u >> 6, dd = u & 63;
    wrow[r][dd] = w[kk[r] * DDIM + dc + dd];
  }
  __syncthreads();

  const float* inb = in + b * BSTRIDE + hw0;
  float* outb = outq + b * BSTRIDE + hw0;
  const int hwl = t & 63, dl = t >> 6;
  double lsum = 0.0;
#pragma unroll
  for (int dd = 0; dd < 64; dd += 4) {
    int d = dc + dd + dl;
    float x = inb[d * HWDIM + hwl];
    float wv = wrow[hwl][dd + dl];
    float diff = __fsub_rn(wv, x);               // fl(quantized - x)
    outb[d * HWDIM + hwl] = __fadd_rn(x, diff);  // fl(x + fl(q - x)) == np
    lsum += (double)diff * (double)diff;
  }
  red[t] = lsum;
  __syncthreads();
  for (int s = 128; s > 0; s >>= 1) {
    if (t < s) red[t] += red[t + s];
    __syncthreads();
  }
  if (t == 0) atomicAdd(loss, red[0]);
}

__global__ void k_final(const int* __restrict__ hist, const double* __restrict__ loss,
                        float* __restrict__ out) {
  __shared__ double red[256];
  int t = threadIdx.x;
  double s = 0.0;
  for (int i = t; i < KCODES; i += 256) {
    double p = (double)hist[i] * (1.0 / 32768.0);
    s += p * log(p + 1e-10);
  }
  red[t] = s;
  __syncthreads();
  for (int st = 128; st > 0; st >>= 1) {
    if (t < st) red[t] += red[t + st];
    __syncthreads();
  }
  if (t == 0) {
    out[8388609] = (float)exp(-red[0]);
    double m = *loss / 8388608.0;
    out[0] = (float)(1.25 * m);   // q_latent + 0.25 * e_latent, identical values
  }
}

extern "C" void kernel_launch(void* const* d_in, const int* in_sizes, int n_in,
                              void* d_out, int out_size, void* d_ws, size_t ws_size,
                              hipStream_t stream) {
  const float* in = (const float*)d_in[0];   // [32,256,32,32]
  const float* w  = (const float*)d_in[1];   // [1024,256]
  float* out = (float*)d_out;

  char* wsb = (char*)d_ws;
  float*    wT     = (float*)   (wsb + 0);
  float*    ssp    = (float*)   (wsb + 1048576);
  unsigned* kkarr  = (unsigned*)(wsb + 1052672);
  int*      wlist  = (int*)     (wsb + 1183744);
  int*      hist   = (int*)     (wsb + 1314816);
  int*      plist  = (int*)     (wsb + 1318912);
  double*   loss   = (double*)  (wsb + 1449984);
  int*      wcount = (int*)     (wsb + 1449992);
  int*      pcount = (int*)     (wsb + 1449996);

  // w split scratch in (not-yet-written) encodings region of d_out
  char* ob = (char*)d_out + 33554448;
  unsigned short* wh8 = (unsigned short*)(ob + 0);
  unsigned short* wl8 = (unsigned short*)(ob + 524288);
  float* encp = out + 8388610;

  k_prep<<<dim3(128), dim3(256), 0, stream>>>(w, wT, ssp, hist, loss, wcount, pcount, wh8, wl8);
  k_argmfma<<<dim3(1024), dim3(256), 0, stream>>>(in, wh8, wl8, ssp, kkarr,
                                                  wlist, wcount, plist, pcount);
  k_fallback<<<dim3(1024), dim3(256), 0, stream>>>(in, w, wT, ssp, wlist, wcount,
                                                   plist, pcount, kkarr);
  k_quantenc<<<dim3(2048), dim3(256), 0, stream>>>(in, w, kkarr, hist, encp,
                                                   out + 1, loss);
  k_final<<<dim3(1), dim3(256), 0, stream>>>(hist, loss, out);
}

// Round 9
// 314.910 us; speedup vs baseline: 1.4782x; 1.4782x over previous
//
#include <hip/hip_runtime.h>
#include <hip/hip_bf16.h>

#define HWDIM 1024             // 32*32
#define DDIM 256
#define KCODES 1024
#define NROWS 32768            // 32 * 1024
#define BSTRIDE (DDIM * HWDIM) // per-batch stride = 262144
#define GUARD 1.5e-4f          // certified gap (covers 2x dist roundings @256 + split err)

typedef __attribute__((ext_vector_type(8))) short short8;
typedef __attribute__((ext_vector_type(4))) float f32x4;
typedef unsigned long long ull;

// ---- ws byte layout ----
// wT     @0        (1048576)  fp32 codebook transposed [256][1024] (full fallback)
// ss     @1048576  (4096)     ||e_k||^2 numpy-pairwise
// kkarr  @1052672  (131072)   final code index per row (u32)
// wlist  @1183744  (131072)   worklist: rows needing FULL exact rescan
// hist   @1314816  (4096)
// plist  @1318912  (131072)   pairlist: rows needing exact {k1,k2} compare  (n | k2<<16)
// loss   @1449984  (8)        double
// wcount @1449992  (4)
// pcount @1449996  (4)
// ---- scratch in d_out encodings region (fully overwritten later by k_quantenc) ----
// ob = (char*)d_out + 33554448: wh8 @0 (524288), wl8 @524288 (524288)

__device__ __forceinline__ unsigned short f2bf(float v) {
  __hip_bfloat16 b = __float2bfloat16(v);
  return *reinterpret_cast<unsigned short*>(&b);
}
__device__ __forceinline__ float bf2f(unsigned short u) {
  __hip_bfloat16 b;
  *reinterpret_cast<unsigned short*>(&b) = u;
  return __bfloat162float(b);
}
__device__ __forceinline__ ull pk(float d, int k) {
  unsigned ub = __float_as_uint(d);
  ub = (ub & 0x80000000u) ? ~ub : (ub | 0x80000000u);  // monotone total order
  return ((ull)ub << 32) | (unsigned)k;
}
__device__ __forceinline__ float keyq(ull key) {
  unsigned ub = (unsigned)(key >> 32);
  unsigned orig = (ub & 0x80000000u) ? (ub & 0x7FFFFFFFu) : ~ub;
  return __uint_as_float(orig);
}
__device__ __forceinline__ float keyq32(unsigned ub) {
  unsigned orig = (ub & 0x80000000u) ? (ub & 0x7FFFFFFFu) : ~ub;
  return __uint_as_float(orig);
}

// numpy-exact pairwise sum of squares over 128 elements
__device__ __forceinline__ float pair128_sq(const float* p, int stride) {
  float a[8];
#pragma unroll
  for (int j = 0; j < 8; ++j) { float v = p[j * stride]; a[j] = __fmul_rn(v, v); }
  for (int i = 8; i < 128; i += 8) {
#pragma unroll
    for (int j = 0; j < 8; ++j) {
      float v = p[(i + j) * stride];
      a[j] = __fadd_rn(a[j], __fmul_rn(v, v));
    }
  }
  float s01 = __fadd_rn(a[0], a[1]), s23 = __fadd_rn(a[2], a[3]);
  float s45 = __fadd_rn(a[4], a[5]), s67 = __fadd_rn(a[6], a[7]);
  return __fadd_rn(__fadd_rn(s01, s23), __fadd_rn(s45, s67));
}

// prep: w bf16 hi/lo split [oct][k][8], wT transpose, ss, inits. grid 128.
__global__ __launch_bounds__(256) void k_prep(
    const float* __restrict__ w, float* __restrict__ wT, float* __restrict__ ss,
    int* __restrict__ hist, double* __restrict__ loss,
    int* __restrict__ wcount, int* __restrict__ pcount,
    unsigned short* __restrict__ wh8, unsigned short* __restrict__ wl8) {
  __shared__ float tile[64][65];
  const int t = threadIdx.x;
  int g = blockIdx.x * 256 + t;   // 32768 = 1024 k x 32 octets
  {
    int k = g >> 5, oct = g & 31;
    const float* p = w + k * DDIM + oct * 8;
    short8 hv, lv;
#pragma unroll
    for (int j = 0; j < 8; ++j) {
      float v = p[j];
      unsigned short h = f2bf(v);
      unsigned short l = f2bf(__fsub_rn(v, bf2f(h)));
      hv[j] = (short)h; lv[j] = (short)l;
    }
    *(short8*)&wh8[oct * 8192 + k * 8] = hv;
    *(short8*)&wl8[oct * 8192 + k * 8] = lv;
  }
  if (g < KCODES) {
    hist[g] = 0;
    const float* p = w + g * DDIM;
    ss[g] = __fadd_rn(pair128_sq(p, 1), pair128_sq(p + 128, 1));
  }
  if (g == 0) { *loss = 0.0; *wcount = 0; *pcount = 0; }
  // transpose (blocks 0..63): w[k][d] -> wT[d][k], 64x64 tiles
  if (blockIdx.x < 64) {
    const int k0 = (blockIdx.x & 15) * 64, d0 = (blockIdx.x >> 4) * 64;
    const int c = t & 63, r = t >> 6;
#pragma unroll
    for (int m = 0; m < 16; ++m)
      tile[r + m * 4][c] = w[(k0 + r + m * 4) * DDIM + d0 + c];
    __syncthreads();
#pragma unroll
    for (int m = 0; m < 16; ++m)
      wT[(size_t)(d0 + r + m * 4) * KCODES + k0 + c] = tile[c][r + m * 4];
  }
}

// single-pass MFMA argmin, m97-style pipelined: block = 512 thr (8 waves) x
// 128 rows, grid 256 (1 block/CU). A (each wave's 16 rows, full K, h+l) lives
// in 64 VGPRs, loaded once via LDS transpose. B streams through a 2x64KB LDS
// double buffer in 16 steps of 64 codes: next tile's global loads issue
// BEFORE the current tile's 96 MFMAs (reg-staged async split), ds_write after,
// one barrier per step. B L2 traffic halves to 256 MB. Top-3 fold identical.
__global__ __launch_bounds__(512, 2) void k_argmfma(
    const float* __restrict__ in,
    const unsigned short* __restrict__ wh8, const unsigned short* __restrict__ wl8,
    const float* __restrict__ ss, unsigned* __restrict__ kkarr,
    int* __restrict__ wlist, int* __restrict__ wcount,
    int* __restrict__ plist, int* __restrict__ pcount) {
  // smem: buf0 @0 (64KB: Bh 32KB + Bl 32KB), buf1 @65536 (64KB)
  // A-staging overlay: Ah @0 (64KB, [oct32][row128][8]), Al @65536 (64KB)
  __shared__ __align__(16) char smem[131072];
  __shared__ __align__(16) float ss_l[1024];
  __shared__ ull best1[128], best2[128];
  __shared__ unsigned best3[128];

  const int t = threadIdx.x;
  const int n0 = blockIdx.x * 128;      // 128 | 1024 -> single batch per block
  const int b = n0 >> 10, hw0 = n0 & 1023;

  const int wv = t >> 6, ln = t & 63;
  const int rw = wv * 16;                // wave's 16-row slice
  const int l15 = ln & 15, quad = ln >> 4;

  unsigned short* Ah = (unsigned short*)smem;
  unsigned short* Al = (unsigned short*)(smem + 65536);

  // ---- stage x -> bf16 h/l split into LDS (identical h/l formulas) ----
  {
    const int hw = t & 127, dg = t >> 7;  // 128 rows, 4 d-groups of 64
    const float* xp = in + b * BSTRIDE + hw0 + hw;
#pragma unroll
    for (int dd = 0; dd < 64; dd += 2) {
      int d = dg * 64 + dd;
      float f0 = __builtin_nontemporal_load(&xp[d * HWDIM]);
      float f1 = __builtin_nontemporal_load(&xp[(d + 1) * HWDIM]);
      unsigned short h0 = f2bf(f0);
      unsigned short l0 = f2bf(__fsub_rn(f0, bf2f(h0)));
      unsigned short h1 = f2bf(f1);
      unsigned short l1 = f2bf(__fsub_rn(f1, bf2f(h1)));
      int base = ((d >> 3) * 128 + hw) * 8 + (d & 7);   // d even -> u32 pack ok
      *(unsigned*)&Ah[base] = (unsigned)h0 | ((unsigned)h1 << 16);
      *(unsigned*)&Al[base] = (unsigned)l0 | ((unsigned)l1 << 16);
    }
  }
  *(float2*)&ss_l[t * 2] = *(const float2*)&ss[t * 2];
  if (t < 128) { best1[t] = ~0ull; best2[t] = ~0ull; best3[t] = 0xFFFFFFFFu; }
  __syncthreads();

  // ---- A fragments to registers: 16 ds_read_b128 per lane, held throughout ----
  short8 afh[8], afl[8];
  {
    const int row = rw + l15;
#pragma unroll
    for (int ki = 0; ki < 8; ++ki) {
      int obase = ki * 4 + quad;
      afh[ki] = *(const short8*)&Ah[(obase * 128 + row) * 8];
      afl[ki] = *(const short8*)&Al[(obase * 128 + row) * 8];
    }
  }
  // chunk-0 B loads can fly while the ds_reads above complete
  short8 s0h[4], s0l[4];
#pragma unroll
  for (int j = 0; j < 4; ++j) {
    int u = j * 512 + t;                 // unit: obase = u>>6, code = u&63
    int ob = u >> 6, c = u & 63;
    s0h[j] = *(const short8*)&wh8[ob * 8192 + c * 8];
    s0l[j] = *(const short8*)&wl8[ob * 8192 + c * 8];
  }
  __syncthreads();   // all A-frag reads done -> safe to overwrite with B buf0

  {
    unsigned short* Bh0 = (unsigned short*)smem;
    unsigned short* Bl0 = (unsigned short*)(smem + 32768);
#pragma unroll
    for (int j = 0; j < 4; ++j) {
      int u = j * 512 + t;
      *(short8*)&Bh0[u * 8] = s0h[j];
      *(short8*)&Bl0[u * 8] = s0l[j];
    }
  }
  __syncthreads();   // chunk 0 visible

  ull rb1[4], rb2[4];                    // running top-2 per reg row slot
  unsigned rb3[4];                       // 3rd-best DIST KEY only (no index)
#pragma unroll
  for (int i = 0; i < 4; ++i) { rb1[i] = ~0ull; rb2[i] = ~0ull; rb3[i] = 0xFFFFFFFFu; }

  int cur = 0;
  for (int s = 0; s < 16; ++s) {         // 16 x 64-code tiles
    const int cb = s * 64;
    // issue next tile's loads BEFORE compute (latency hides under MFMAs)
    short8 sh_[4], sl_[4];
    if (s < 15) {
      const int cb1 = cb + 64;
#pragma unroll
      for (int j = 0; j < 4; ++j) {
        int u = j * 512 + t;
        int ob = u >> 6, c = u & 63;
        sh_[j] = *(const short8*)&wh8[ob * 8192 + (cb1 + c) * 8];
        sl_[j] = *(const short8*)&wl8[ob * 8192 + (cb1 + c) * 8];
      }
    }

    const unsigned short* Bh = (const unsigned short*)(smem + cur * 65536);
    const unsigned short* Bl = (const unsigned short*)(smem + cur * 65536 + 32768);
    f32x4 acc[4];
#pragma unroll
    for (int ct = 0; ct < 4; ++ct) acc[ct] = (f32x4){0.f, 0.f, 0.f, 0.f};

#pragma unroll
    for (int ki = 0; ki < 8; ++ki) {
      const int obase = ki * 4 + quad;
      short8 bh[4], bl[4];
#pragma unroll
      for (int ct = 0; ct < 4; ++ct) {
        int uo = (obase * 64 + ct * 16 + l15) * 8;
        bh[ct] = *(const short8*)&Bh[uo];
        bl[ct] = *(const short8*)&Bl[uo];
      }
#pragma unroll
      for (int ct = 0; ct < 4; ++ct) {
        acc[ct] = __builtin_amdgcn_mfma_f32_16x16x32_bf16(afh[ki], bh[ct], acc[ct], 0, 0, 0);
        acc[ct] = __builtin_amdgcn_mfma_f32_16x16x32_bf16(afh[ki], bl[ct], acc[ct], 0, 0, 0);
        acc[ct] = __builtin_amdgcn_mfma_f32_16x16x32_bf16(afl[ki], bh[ct], acc[ct], 0, 0, 0);
      }
    }

    // fold this tile's 64 codes into running per-row top-3 (lane-local)
    float sv[4];
#pragma unroll
    for (int ct = 0; ct < 4; ++ct) sv[ct] = ss_l[cb + ct * 16 + l15];
#pragma unroll
    for (int reg = 0; reg < 4; ++reg) {
      ull b1 = rb1[reg], b2 = rb2[reg];
      unsigned b3 = rb3[reg];
#pragma unroll
      for (int ct = 0; ct < 4; ++ct) {
        float q = fmaf(-2.f, acc[ct][reg], sv[ct]);
        ull key = pk(q, cb + ct * 16 + l15);
        unsigned k32 = (unsigned)(key >> 32);
        if (key < b1)      { b3 = (unsigned)(b2 >> 32); b2 = b1; b1 = key; }
        else if (key < b2) { b3 = (unsigned)(b2 >> 32); b2 = key; }
        else if (k32 < b3) { b3 = k32; }
      }
      rb1[reg] = b1; rb2[reg] = b2; rb3[reg] = b3;
    }

    // write next tile into the other buffer (waitcnt auto-inserted on use)
    if (s < 15) {
      unsigned short* BhN = (unsigned short*)(smem + (cur ^ 1) * 65536);
      unsigned short* BlN = (unsigned short*)(smem + (cur ^ 1) * 65536 + 32768);
#pragma unroll
      for (int j = 0; j < 4; ++j) {
        int u = j * 512 + t;
        *(short8*)&BhN[u * 8] = sh_[j];
        *(short8*)&BlN[u * 8] = sl_[j];
      }
    }
    __syncthreads();
    cur ^= 1;
  }

  // three-pass block merge: global best, 2nd, 3rd(dist-key only)
#pragma unroll
  for (int reg = 0; reg < 4; ++reg)
    atomicMin(&best1[rw + quad * 4 + reg], rb1[reg]);
  __syncthreads();
#pragma unroll
  for (int reg = 0; reg < 4; ++reg) {
    int row = rw + quad * 4 + reg;
    ull sub = (rb1[reg] == best1[row]) ? rb2[reg] : rb1[reg];
    atomicMin(&best2[row], sub);
  }
  __syncthreads();
#pragma unroll
  for (int reg = 0; reg < 4; ++reg) {
    int row = rw + quad * 4 + reg;
    ull b1 = best1[row], b2 = best2[row];
    unsigned c = (rb1[reg] != b1 && rb1[reg] != b2) ? (unsigned)(rb1[reg] >> 32)
               : ((rb2[reg] != b1 && rb2[reg] != b2) ? (unsigned)(rb2[reg] >> 32)
                                                     : rb3[reg]);
    atomicMin(&best3[row], c);
  }
  __syncthreads();
  if (t < 128) {
    ull k1 = best1[t];
    kkarr[n0 + t] = (unsigned)(k1 & 0xFFFFFFFFull);
    float q1 = keyq(k1);
    if (!(keyq(best2[t]) - q1 > GUARD)) {
      if (keyq32(best3[t]) - q1 > GUARD) {
        // exact argmin is provably in {k1, k2}: cheap pair recheck
        int p = atomicAdd(pcount, 1);
        plist[p] = (n0 + t) | ((int)(best2[t] & 0xFFFFFFFFull) << 16);
      } else {
        int p = atomicAdd(wcount, 1);
        wlist[p] = n0 + t;
      }
    }
  }
}

// recheck kernel: cheap exact {k1,k2} compare for pair rows, full 1024-code
// exact rescan only for rows with gap3 <= GUARD. grid 1024.
// Both paths replicate the verified numpy-exact FP op order.
__global__ __launch_bounds__(256) void k_fallback(
    const float* __restrict__ in, const float* __restrict__ w,
    const float* __restrict__ wT, const float* __restrict__ ss,
    const int* __restrict__ wlist, const int* __restrict__ wcount,
    const int* __restrict__ plist, const int* __restrict__ pcount,
    unsigned* __restrict__ kkarr) {
  __shared__ float xrow[256];
  __shared__ float rsh;
  __shared__ ull bmin;
  __shared__ ull pkeys[2];
  const int t = threadIdx.x;

  // ---- pair rows: exact dist for k1,k2 only (identical op order to full path) ----
  const int pc = *pcount;
  for (int i = blockIdx.x; i < pc; i += gridDim.x) {
    const int pe = plist[i];
    const int n = pe & 0xFFFF;
    const unsigned k2 = ((unsigned)pe) >> 16;
    const unsigned k1 = kkarr[n];
    const int b = n >> 10, hw = n & 1023;
    xrow[t] = in[b * BSTRIDE + t * HWDIM + hw];
    __syncthreads();
    if (t == 0) rsh = __fadd_rn(pair128_sq(xrow, 1), pair128_sq(xrow + 128, 1));
    __syncthreads();
    if (t < 2) {
      unsigned k = t ? k2 : k1;
      const float* wr = w + (size_t)k * DDIM;   // same values as wT column k
      float m = 0.f;
      for (int d = 0; d < 256; ++d) m = fmaf(xrow[d], wr[d], m);
      float dist = fmaf(-2.f, m, __fadd_rn(rsh, ss[k]));
      pkeys[t] = pk(dist, (int)k);
    }
    __syncthreads();
    if (t == 0) {
      ull kmin = pkeys[0] < pkeys[1] ? pkeys[0] : pkeys[1];
      kkarr[n] = (unsigned)(kmin & 0xFFFFFFFFull);
    }
    __syncthreads();
  }

  // ---- full rows: exact rescan of all 1024 codes (unchanged verified path) ----
  const int cnt = *wcount;
  for (int i = blockIdx.x; i < cnt; i += gridDim.x) {
    const int n = wlist[i];
    const int b = n >> 10, hw = n & 1023;
    xrow[t] = in[b * BSTRIDE + t * HWDIM + hw];
    if (t == 0) bmin = ~0ull;
    __syncthreads();
    if (t == 0) rsh = __fadd_rn(pair128_sq(xrow, 1), pair128_sq(xrow + 128, 1));
    __syncthreads();
    float m[4] = {0.f, 0.f, 0.f, 0.f};
    for (int d = 0; d < 256; ++d) {
      float xv = xrow[d];
      const float* wd = wT + (size_t)d * KCODES + t;
      m[0] = fmaf(xv, wd[0], m[0]);
      m[1] = fmaf(xv, wd[256], m[1]);
      m[2] = fmaf(xv, wd[512], m[2]);
      m[3] = fmaf(xv, wd[768], m[3]);
    }
    ull lb = ~0ull;
#pragma unroll
    for (int j = 0; j < 4; ++j) {
      int k = t + j * 256;
      float dist = fmaf(-2.f, m[j], __fadd_rn(rsh, ss[k]));
      ull key = pk(dist, k);
      if (key < lb) lb = key;
    }
    atomicMin(&bmin, lb);
    __syncthreads();
    if (t == 0) kkarr[n] = (unsigned)(bmin & 0xFFFFFFFFull);
    __syncthreads();
  }
}

// fused streaming epilogue: one-hot enc rows written DIRECTLY (zeros + the one),
// quantized_st, loss, hist. block = 64 rows x (64-d chunk, 256-code chunk). grid 2048.
__global__ __launch_bounds__(256) void k_quantenc(
    const float* __restrict__ in, const float* __restrict__ w,
    const unsigned* __restrict__ kkarr, int* __restrict__ hist,
    float* __restrict__ enc, float* __restrict__ outq, double* __restrict__ loss) {
  __shared__ float wrow[64][65];
  __shared__ unsigned kk[64];
  __shared__ double red[256];

  const int t = threadIdx.x;
  const int q = blockIdx.x & 3;
  const int n0 = (blockIdx.x >> 2) * 64;
  const int dc = q * 64;          // d chunk for outq/loss
  const int c0 = q * 256;         // code chunk for enc rows
  const int b = n0 >> 10, hw0 = n0 & 1023;

  if (t < 64) kk[t] = kkarr[n0 + t];
  __syncthreads();

  if (q == 0 && t < 64) atomicAdd(&hist[kk[t]], 1);

  // enc: 64 rows x 256 codes = 8192 float2 (base is 8B-aligned only -> float2)
#pragma unroll 4
  for (int m = 0; m < 32; ++m) {
    int u = m * 256 + t;
    int r = u >> 7, c2 = u & 127;
    int cbase = c0 + c2 * 2;
    unsigned kr = kk[r];
    float2 v;
    v.x = (cbase == (int)kr) ? 1.0f : 0.0f;
    v.y = (cbase + 1 == (int)kr) ? 1.0f : 0.0f;
    *(float2*)&enc[(size_t)(n0 + r) * 1024 + cbase] = v;
  }

  // stage the 64 codebook rows' 64-d slice (gather; w is L2-resident)
#pragma unroll
  for (int m = 0; m < 16; ++m) {
    int u = t + m * 256;
    int r = u >> 6, dd = u & 63;
    wrow[r][dd] = w[kk[r] * DDIM + dc + dd];
  }
  __syncthreads();

  const float* inb = in + b * BSTRIDE + hw0;
  float* outb = outq + b * BSTRIDE + hw0;
  const int hwl = t & 63, dl = t >> 6;
  double lsum = 0.0;
#pragma unroll
  for (int dd = 0; dd < 64; dd += 4) {
    int d = dc + dd + dl;
    float x = inb[d * HWDIM + hwl];
    float wv = wrow[hwl][dd + dl];
    float diff = __fsub_rn(wv, x);               // fl(quantized - x)
    outb[d * HWDIM + hwl] = __fadd_rn(x, diff);  // fl(x + fl(q - x)) == np
    lsum += (double)diff * (double)diff;
  }
  red[t] = lsum;
  __syncthreads();
  for (int s = 128; s > 0; s >>= 1) {
    if (t < s) red[t] += red[t + s];
    __syncthreads();
  }
  if (t == 0) atomicAdd(loss, red[0]);
}

__global__ void k_final(const int* __restrict__ hist, const double* __restrict__ loss,
                        float* __restrict__ out) {
  __shared__ double red[256];
  int t = threadIdx.x;
  double s = 0.0;
  for (int i = t; i < KCODES; i += 256) {
    double p = (double)hist[i] * (1.0 / 32768.0);
    s += p * log(p + 1e-10);
  }
  red[t] = s;
  __syncthreads();
  for (int st = 128; st > 0; st >>= 1) {
    if (t < st) red[t] += red[t + st];
    __syncthreads();
  }
  if (t == 0) {
    out[8388609] = (float)exp(-red[0]);
    double m = *loss / 8388608.0;
    out[0] = (float)(1.25 * m);   // q_latent + 0.25 * e_latent, identical values
  }
}

extern "C" void kernel_launch(void* const* d_in, const int* in_sizes, int n_in,
                              void* d_out, int out_size, void* d_ws, size_t ws_size,
                              hipStream_t stream) {
  const float* in = (const float*)d_in[0];   // [32,256,32,32]
  const float* w  = (const float*)d_in[1];   // [1024,256]
  float* out = (float*)d_out;

  char* wsb = (char*)d_ws;
  float*    wT     = (float*)   (wsb + 0);
  float*    ssp    = (float*)   (wsb + 1048576);
  unsigned* kkarr  = (unsigned*)(wsb + 1052672);
  int*      wlist  = (int*)     (wsb + 1183744);
  int*      hist   = (int*)     (wsb + 1314816);
  int*      plist  = (int*)     (wsb + 1318912);
  double*   loss   = (double*)  (wsb + 1449984);
  int*      wcount = (int*)     (wsb + 1449992);
  int*      pcount = (int*)     (wsb + 1449996);

  // w split scratch in (not-yet-written) encodings region of d_out
  char* ob = (char*)d_out + 33554448;
  unsigned short* wh8 = (unsigned short*)(ob + 0);
  unsigned short* wl8 = (unsigned short*)(ob + 524288);
  float* encp = out + 8388610;

  k_prep<<<dim3(128), dim3(256), 0, stream>>>(w, wT, ssp, hist, loss, wcount, pcount, wh8, wl8);
  k_argmfma<<<dim3(256), dim3(512), 0, stream>>>(in, wh8, wl8, ssp, kkarr,
                                                 wlist, wcount, plist, pcount);
  k_fallback<<<dim3(1024), dim3(256), 0, stream>>>(in, w, wT, ssp, wlist, wcount,
                                                   plist, pcount, kkarr);
  k_quantenc<<<dim3(2048), dim3(256), 0, stream>>>(in, w, kkarr, hist, encp,
                                                   out + 1, loss);
  k_final<<<dim3(1), dim3(256), 0, stream>>>(hist, loss, out);
}